// Round 4
// baseline (206.454 us; speedup 1.0000x reference)
//
#include <hip/hip_runtime.h>
#include <hip/hip_bf16.h>
#include <math.h>

#define NN 8192
#define SS 50
#define DD 64
#define MM 20000
#define TAU_INV 2.0f
#define ALPHA 0.5f
#define SQSCALE 1.6986437f  // sqrt(2*tau_inv*log2(e)); folded into bf16 inputs
#define LN2 0.69314718056f

typedef __attribute__((ext_vector_type(8))) short short8;  // 8 bf16
typedef __attribute__((ext_vector_type(4))) float f32x4;
typedef __attribute__((ext_vector_type(2))) float f32x2;

__device__ __forceinline__ float wred64(float v) {
#pragma unroll
  for (int m = 1; m < 64; m <<= 1) v += __shfl_xor(v, m, 64);
  return v;
}
__device__ __forceinline__ float wredmax64(float v) {
#pragma unroll
  for (int m = 1; m < 64; m <<= 1) v = fmaxf(v, __shfl_xor(v, m, 64));
  return v;
}

// ---------------- q[t][m] = dot(h_t[m], att_t[D:2D]) ------------------------
__global__ __launch_bounds__(256) void q_kernel(
    const float* __restrict__ h1, const float* __restrict__ h2,
    const float* __restrict__ att0, const float* __restrict__ att1,
    float* __restrict__ q) {
  int gw = blockIdx.x * 4 + (threadIdx.x >> 6);
  int lane = threadIdx.x & 63;
  const float* h = gw < MM ? h1 : h2;
  const float* att = gw < MM ? att0 : att1;
  int row = gw < MM ? gw : gw - MM;
  float v = h[(size_t)row * DD + lane] * att[DD + lane];
  float s = wred64(v);
  if (lane == 0) q[gw] = s;
}

// ---------------- intra attention + ELU -------------------------------------
__global__ __launch_bounds__(256) void intra_kernel(
    const float* __restrict__ h0, const float* __restrict__ h1,
    const float* __restrict__ h2, const int* __restrict__ nei0,
    const int* __restrict__ nei1, const float* __restrict__ att0,
    const float* __restrict__ att1, const float* __restrict__ q,
    float* __restrict__ e0, float* __restrict__ e1) {
  __shared__ float wls[4][SS];
  __shared__ int ils[4][SS];
  const int w = threadIdx.x >> 6, lane = threadIdx.x & 63;
  const int n = blockIdx.x * 4 + w;
  const int type = blockIdx.y;
  const float* __restrict__ h = type ? h2 : h1;
  const int* __restrict__ nei = type ? nei1 : nei0;
  const float* __restrict__ att = type ? att1 : att0;
  const float* __restrict__ qq = q + (size_t)type * MM;
  float* __restrict__ e = type ? e1 : e0;

  float r = h0[(size_t)n * DD + lane];
  float ref = wred64(r * att[lane]);

  float logit = -1e30f;
  int myidx = 0;
  if (lane < SS) {
    myidx = nei[(size_t)n * SS + lane];
    float l = ref + qq[myidx];
    logit = l > 0.f ? l : 0.01f * l;  // leaky_relu slope 0.01
  }
  float mx = wredmax64(logit);
  float ev = lane < SS ? __expf(logit - mx) : 0.f;
  float sum = wred64(ev);
  if (lane < SS) {
    wls[w][lane] = ev / sum;
    ils[w][lane] = myidx;
  }
  __syncthreads();
  float acc = 0.f;
#pragma unroll 10
  for (int s = 0; s < SS; ++s)
    acc = fmaf(wls[w][s], h[(size_t)ils[w][s] * DD + lane], acc);
  e[(size_t)n * DD + lane] = acc > 0.f ? acc : expm1f(acc);  // ELU
}

// ---------------- prep: scaled normalized bf16 copies + diag partials -------
// grid N/4 = 2048 blocks. diagPart layout [p][block] (no atomics).
__global__ __launch_bounds__(256) void prep_kernel(
    const float* __restrict__ h0, const float* __restrict__ e0,
    const float* __restrict__ e1, unsigned short* __restrict__ An,
    unsigned short* __restrict__ Bn, unsigned short* __restrict__ Cn,
    float* __restrict__ diagPart) {
  __shared__ float sm[4][3];
  const int w = threadIdx.x >> 6, lane = threadIdx.x & 63;
  const int n = blockIdx.x * 4 + w;
  float v0 = h0[(size_t)n * DD + lane];
  float v1 = e0[(size_t)n * DD + lane];
  float v2 = e1[(size_t)n * DD + lane];
  float s00 = wred64(v0 * v0);
  float s11 = wred64(v1 * v1);
  float s22 = wred64(v2 * v2);
  float d01 = wred64(v0 * v1);
  float d02 = wred64(v0 * v2);
  float d12 = wred64(v1 * v2);
  float i0 = rsqrtf(s00), i1 = rsqrtf(s11), i2 = rsqrtf(s22);
  union { __hip_bfloat16 b; unsigned short u; } c0, c1, c2;
  c0.b = __float2bfloat16(v0 * i0 * SQSCALE);
  c1.b = __float2bfloat16(v1 * i1 * SQSCALE);
  c2.b = __float2bfloat16(v2 * i2 * SQSCALE);
  An[(size_t)n * DD + lane] = c0.u;
  Bn[(size_t)n * DD + lane] = c1.u;
  Cn[(size_t)n * DD + lane] = c2.u;
  if (lane == 0) {
    sm[w][0] = d01 * i0 * i1 * TAU_INV;
    sm[w][1] = d02 * i0 * i2 * TAU_INV;
    sm[w][2] = d12 * i1 * i2 * TAU_INV;
  }
  __syncthreads();
  if (threadIdx.x < 3)
    diagPart[threadIdx.x * (NN / 4) + blockIdx.x] =
        sm[0][threadIdx.x] + sm[1][threadIdx.x] + sm[2][threadIdx.x] +
        sm[3][threadIdx.x];
}

// ---------------- sim via bf16 MFMA: per-block row/col exp-sum partials -----
// grid (N/128, N/512, 3), block 256 = 4 waves (2x2 of 64x64 tiles).
// Inputs pre-scaled so exp2(dot) = exp(sim/tau). NO global atomics:
// rowPart[(p*16+by)][row], colPart[((p*16+by)*64+bx)][col'].
__global__ __launch_bounds__(256) void sim_mfma_kernel(
    const unsigned short* __restrict__ An, const unsigned short* __restrict__ Bn,
    const unsigned short* __restrict__ Cn, float* __restrict__ rowPart,
    float* __restrict__ colPart) {
  __shared__ float colLds[512];
  __shared__ float rowLds[128];
  const int p = blockIdx.z;
  const unsigned short *a, *b;
  if (p == 0)      { a = An; b = Bn; }
  else if (p == 1) { a = An; b = Cn; }
  else             { a = Bn; b = Cn; }

  const int tid = threadIdx.x;
  const int w = tid >> 6, lane = tid & 63;
  const int wr = w >> 1, wc = w & 1;
  const int lr = lane & 15, lk = lane >> 4;
  const int i0 = blockIdx.x * 128 + wr * 64;
  const int jbase = blockIdx.y * 512;

  for (int i = tid; i < 512; i += 256) colLds[i] = 0.f;
  if (tid < 128) rowLds[tid] = 0.f;
  __syncthreads();

  // A fragments: lane holds row (i0+rb*16+lr), k = kh*32 + lk*8 .. +7
  short8 afrag[4][2];
#pragma unroll
  for (int rb = 0; rb < 4; ++rb)
#pragma unroll
    for (int kh = 0; kh < 2; ++kh)
      afrag[rb][kh] = *reinterpret_cast<const short8*>(
          a + (size_t)(i0 + rb * 16 + lr) * DD + kh * 32 + lk * 8);

  f32x2 rowacc[4][2];
#pragma unroll
  for (int rb = 0; rb < 4; ++rb) {
    rowacc[rb][0] = (f32x2){0.f, 0.f};
    rowacc[rb][1] = (f32x2){0.f, 0.f};
  }
  float colv[4][4];

#pragma unroll
  for (int jt = 0; jt < 4; ++jt) {
    const int j0 = jbase + jt * 128 + wc * 64;
#pragma unroll
    for (int cb = 0; cb < 4; ++cb) {
      const unsigned short* bp = b + (size_t)(j0 + cb * 16 + lr) * DD + lk * 8;
      const short8 b0 = *reinterpret_cast<const short8*>(bp);
      const short8 b1 = *reinterpret_cast<const short8*>(bp + 32);
      f32x4 acc[4];
#pragma unroll
      for (int rb = 0; rb < 4; ++rb) {
        acc[rb] = __builtin_amdgcn_mfma_f32_16x16x32_bf16(
            afrag[rb][0], b0, (f32x4){0.f, 0.f, 0.f, 0.f}, 0, 0, 0);
        acc[rb] = __builtin_amdgcn_mfma_f32_16x16x32_bf16(
            afrag[rb][1], b1, acc[rb], 0, 0, 0);
      }
      // C/D layout: col = lr, row = lk*4 + g
      f32x2 cp = {0.f, 0.f};
#pragma unroll
      for (int rb = 0; rb < 4; ++rb) {
        f32x2 eva = {__builtin_amdgcn_exp2f(acc[rb][0]),
                     __builtin_amdgcn_exp2f(acc[rb][1])};
        f32x2 evb = {__builtin_amdgcn_exp2f(acc[rb][2]),
                     __builtin_amdgcn_exp2f(acc[rb][3])};
        rowacc[rb][0] += eva;
        rowacc[rb][1] += evb;
        cp += eva + evb;
      }
      colv[jt][cb] = cp.x + cp.y;
    }
  }

  // col partials: complete over the 4 lk row-groups, merge wr pair in LDS
#pragma unroll
  for (int jt = 0; jt < 4; ++jt)
#pragma unroll
    for (int cb = 0; cb < 4; ++cb) {
      float v = colv[jt][cb];
      v += __shfl_xor(v, 16, 64);
      v += __shfl_xor(v, 32, 64);
      if (lk == 0) atomicAdd(&colLds[jt * 128 + wc * 64 + cb * 16 + lr], v);
    }
  // row partials: complete over the 16 lr col-lanes, merge wc pair in LDS
#pragma unroll
  for (int rb = 0; rb < 4; ++rb)
#pragma unroll
    for (int g = 0; g < 4; ++g) {
      float v = rowacc[rb][g >> 1][g & 1];
      v += __shfl_xor(v, 1, 64);
      v += __shfl_xor(v, 2, 64);
      v += __shfl_xor(v, 4, 64);
      v += __shfl_xor(v, 8, 64);
      if (lr == 0) atomicAdd(&rowLds[wr * 64 + rb * 16 + lk * 4 + g], v);
    }
  __syncthreads();
  if (tid < 128)
    rowPart[(size_t)(p * 16 + blockIdx.y) * NN + blockIdx.x * 128 + tid] =
        rowLds[tid];
  for (int i = tid; i < 512; i += 256)
    colPart[(size_t)((p * 16 + blockIdx.y) * 64 + blockIdx.x) * 512 + i] =
        colLds[i];
}

// ---------------- semantic attention: sp[t][d] = sum_n tanh(e fc^T + b) -----
__global__ __launch_bounds__(256) void sp_kernel(
    const float* __restrict__ e0, const float* __restrict__ e1,
    const float* __restrict__ fc_w, const float* __restrict__ fc_b,
    float* __restrict__ sp) {
  __shared__ float fcw[64][65];
  __shared__ float es[64][65];
  __shared__ float part[4][64];
  const int t = blockIdx.y;
  const float* __restrict__ e = t ? e1 : e0;
  const int n0 = blockIdx.x * 64;
  const int tid = threadIdx.x;
  for (int i = tid; i < 4096; i += 256) fcw[i >> 6][i & 63] = fc_w[i];
  for (int i = tid; i < 4096; i += 256) {
    int r = i >> 6, c = i & 63;
    es[r][c] = e[(size_t)(n0 + r) * DD + c];
  }
  __syncthreads();
  const int w = tid >> 6, lane = tid & 63;
  const float b = fc_b[lane];
  float partial = 0.f;
  for (int n = w; n < 64; n += 4) {
    float acc = b;
#pragma unroll 8
    for (int k = 0; k < DD; ++k) acc = fmaf(es[n][k], fcw[lane][k], acc);
    acc = fminf(fmaxf(acc, -15.f), 15.f);
    float tt = __expf(2.f * acc);
    partial += (tt - 1.f) * __builtin_amdgcn_rcpf(tt + 1.f);
  }
  part[w][lane] = partial;
  __syncthreads();
  if (tid < 64)
    atomicAdd(&sp[t * DD + tid],
              part[0][tid] + part[1][tid] + part[2][tid] + part[3][tid]);
}

// ---------------- loss partials: reduce rowPart/colPart/diagPart ------------
// grid 216 blocks x 256 (= 6*NN + 6144 units exactly).
__global__ __launch_bounds__(256) void losspart_kernel(
    const float* __restrict__ rowPart, const float* __restrict__ colPart,
    const float* __restrict__ diagPart, float* __restrict__ lossAcc) {
  const int g = blockIdx.x * 256 + threadIdx.x;
  float acc = 0.f;
  if (g < 3 * NN) {
    const int p = g >> 13, r = g & (NN - 1);
    float s = 0.f;
#pragma unroll
    for (int by = 0; by < 16; ++by) s += rowPart[(size_t)(p * 16 + by) * NN + r];
    const float wp = (p == 2) ? ALPHA : 1.f;
    acc = 0.5f * wp * LN2 * __builtin_amdgcn_logf(s);
  } else if (g < 6 * NN) {
    const int gg = g - 3 * NN;
    const int p = gg >> 13, c = gg & (NN - 1);
    const float* base =
        colPart + (size_t)p * (16 * 64 * 512) + (c >> 9) * (64 * 512) + (c & 511);
    float s = 0.f;
#pragma unroll
    for (int bx = 0; bx < 64; ++bx) s += base[bx * 512];
    const float wp = (p == 2) ? ALPHA : 1.f;
    acc = 0.5f * wp * LN2 * __builtin_amdgcn_logf(s);
  } else {
    const int gg = g - 6 * NN;  // < 6144
    const int p = gg >> 11;     // / (NN/4)
    const float wp = (p == 2) ? ALPHA : 1.f;
    acc = -wp * diagPart[gg];
  }
  __shared__ float red[256];
  red[threadIdx.x] = acc;
  __syncthreads();
  for (int s2 = 128; s2 > 0; s2 >>= 1) {
    if (threadIdx.x < s2) red[threadIdx.x] += red[threadIdx.x + s2];
    __syncthreads();
  }
  if (threadIdx.x == 0) atomicAdd(lossAcc, red[0]);
}

// ---------------- z_mc = beta0*e0 + beta1*e1 (+ loss store by block 0) ------
// beta recomputed per block (cheap, L2-hot) to avoid a single-block kernel.
__global__ __launch_bounds__(256) void zmc_kernel(
    const float* __restrict__ e0, const float* __restrict__ e1,
    const float* __restrict__ sp, const float* __restrict__ att_inter,
    const float* __restrict__ lossAcc, float* __restrict__ out) {
  __shared__ float bsh[2];
  const int tid = threadIdx.x;
  if (tid < 64) {
    float a_ = att_inter[tid];
    float s0 = sp[tid] * (1.f / (float)NN) * a_;
    float s1 = sp[DD + tid] * (1.f / (float)NN) * a_;
#pragma unroll
    for (int m = 1; m < 64; m <<= 1) {
      s0 += __shfl_xor(s0, m, 64);
      s1 += __shfl_xor(s1, m, 64);
    }
    if (tid == 0) {
      float mm = fmaxf(s0, s1);
      float b0 = __expf(s0 - mm), b1 = __expf(s1 - mm);
      float inv = 1.f / (b0 + b1);
      bsh[0] = b0 * inv;
      bsh[1] = b1 * inv;
    }
  }
  __syncthreads();
  const float b0 = bsh[0], b1 = bsh[1];
  const int i = blockIdx.x * 256 + tid;
  float4 a = ((const float4*)e0)[i];
  float4 b = ((const float4*)e1)[i];
  float4 o;
  o.x = b0 * a.x + b1 * b.x;
  o.y = b0 * a.y + b1 * b.y;
  o.z = b0 * a.z + b1 * b.z;
  o.w = b0 * a.w + b1 * b.w;
  ((float4*)out)[i] = o;
  if (blockIdx.x == 0 && tid == 0)
    out[(size_t)NN * DD] = lossAcc[0] * (1.f / (float)NN);
}

extern "C" void kernel_launch(void* const* d_in, const int* in_sizes, int n_in,
                              void* d_out, int out_size, void* d_ws,
                              size_t ws_size, hipStream_t stream) {
  const float* h0 = (const float*)d_in[0];
  const float* h1 = (const float*)d_in[1];
  const float* h2 = (const float*)d_in[2];
  const int* nei0 = (const int*)d_in[3];
  const int* nei1 = (const int*)d_in[4];
  const float* att0 = (const float*)d_in[5];
  const float* att1 = (const float*)d_in[6];
  const float* fcw = (const float*)d_in[7];
  const float* fcb = (const float*)d_in[8];
  const float* atti = (const float*)d_in[9];
  float* out = (float*)d_out;

  float* ws = (float*)d_ws;
  float* e0 = ws;                                   // NN*DD
  float* e1 = e0 + (size_t)NN * DD;                 // NN*DD
  float* q = e1 + (size_t)NN * DD;                  // 2*MM = 40000
  unsigned short* An = (unsigned short*)(q + 2 * MM);  // NN*DD bf16 each
  unsigned short* Bn = An + (size_t)NN * DD;
  unsigned short* Cn = Bn + (size_t)NN * DD;
  float* rowPart = (float*)(Cn + (size_t)NN * DD);  // 3*16*NN
  float* colPart = rowPart + (size_t)3 * 16 * NN;   // 3*16*64*512
  float* diagPart = colPart + (size_t)3 * 16 * 64 * 512;  // 3*(NN/4)
  float* sp = diagPart + 3 * (NN / 4);              // 2*DD (zeroed)
  float* lossAcc = sp + 2 * DD;                     // 1    (zeroed)

  hipMemsetAsync(sp, 0, (2 * DD + 1) * sizeof(float), stream);

  q_kernel<<<dim3((2 * MM) / 4), 256, 0, stream>>>(h1, h2, att0, att1, q);
  intra_kernel<<<dim3(NN / 4, 2), 256, 0, stream>>>(h0, h1, h2, nei0, nei1,
                                                    att0, att1, q, e0, e1);
  prep_kernel<<<dim3(NN / 4), 256, 0, stream>>>(h0, e0, e1, An, Bn, Cn,
                                                diagPart);
  sp_kernel<<<dim3(NN / 64, 2), 256, 0, stream>>>(e0, e1, fcw, fcb, sp);
  sim_mfma_kernel<<<dim3(NN / 128, NN / 512, 3), 256, 0, stream>>>(
      An, Bn, Cn, rowPart, colPart);
  losspart_kernel<<<dim3((6 * NN + 6144) / 256), 256, 0, stream>>>(
      rowPart, colPart, diagPart, lossAcc);
  zmc_kernel<<<dim3(NN * DD / 1024), 256, 0, stream>>>(e0, e1, sp, atti,
                                                       lossAcc, out);
}

// Round 5
// 134.888 us; speedup vs baseline: 1.5306x; 1.5306x over previous
//
#include <hip/hip_runtime.h>
#include <hip/hip_bf16.h>
#include <math.h>

#define NN 8192
#define SS 50
#define DD 64
#define MM 20000
#define TAU_INV 2.0f
#define ALPHA 0.5f
#define SQSCALE 1.6986437f  // sqrt(TAU_INV*log2(e)); folded into bf16 inputs
#define LN2 0.69314718056f

typedef __attribute__((ext_vector_type(8))) short short8;  // 8 bf16
typedef __attribute__((ext_vector_type(4))) float f32x4;

__device__ __forceinline__ float wred64(float v) {
#pragma unroll
  for (int m = 1; m < 64; m <<= 1) v += __shfl_xor(v, m, 64);
  return v;
}
__device__ __forceinline__ float wredmax64(float v) {
#pragma unroll
  for (int m = 1; m < 64; m <<= 1) v = fmaxf(v, __shfl_xor(v, m, 64));
  return v;
}

// ---------------- q[t][m] = dot(h_t[m], att_t[D:2D]) ------------------------
__global__ __launch_bounds__(256) void q_kernel(
    const float* __restrict__ h1, const float* __restrict__ h2,
    const float* __restrict__ att0, const float* __restrict__ att1,
    float* __restrict__ q) {
  int gw = blockIdx.x * 4 + (threadIdx.x >> 6);
  int lane = threadIdx.x & 63;
  const float* h = gw < MM ? h1 : h2;
  const float* att = gw < MM ? att0 : att1;
  int row = gw < MM ? gw : gw - MM;
  float v = h[(size_t)row * DD + lane] * att[DD + lane];
  float s = wred64(v);
  if (lane == 0) q[gw] = s;
}

// ---------------- intra attention + ELU -------------------------------------
__global__ __launch_bounds__(256) void intra_kernel(
    const float* __restrict__ h0, const float* __restrict__ h1,
    const float* __restrict__ h2, const int* __restrict__ nei0,
    const int* __restrict__ nei1, const float* __restrict__ att0,
    const float* __restrict__ att1, const float* __restrict__ q,
    float* __restrict__ e0, float* __restrict__ e1) {
  __shared__ float wls[4][SS];
  __shared__ int ils[4][SS];
  const int w = threadIdx.x >> 6, lane = threadIdx.x & 63;
  const int n = blockIdx.x * 4 + w;
  const int type = blockIdx.y;
  const float* __restrict__ h = type ? h2 : h1;
  const int* __restrict__ nei = type ? nei1 : nei0;
  const float* __restrict__ att = type ? att1 : att0;
  const float* __restrict__ qq = q + (size_t)type * MM;
  float* __restrict__ e = type ? e1 : e0;

  float r = h0[(size_t)n * DD + lane];
  float ref = wred64(r * att[lane]);

  float logit = -1e30f;
  int myidx = 0;
  if (lane < SS) {
    myidx = nei[(size_t)n * SS + lane];
    float l = ref + qq[myidx];
    logit = l > 0.f ? l : 0.01f * l;  // leaky_relu slope 0.01
  }
  float mx = wredmax64(logit);
  float ev = lane < SS ? __expf(logit - mx) : 0.f;
  float sum = wred64(ev);
  if (lane < SS) {
    wls[w][lane] = ev / sum;
    ils[w][lane] = myidx;
  }
  __syncthreads();
  float acc = 0.f;
#pragma unroll 10
  for (int s = 0; s < SS; ++s)
    acc = fmaf(wls[w][s], h[(size_t)ils[w][s] * DD + lane], acc);
  e[(size_t)n * DD + lane] = acc > 0.f ? acc : expm1f(acc);  // ELU
}

// ---------------- prep: scaled normalized bf16 copies + diag partials -------
// grid N/4 = 2048 blocks. diagPart layout [p][block] (no atomics).
__global__ __launch_bounds__(256) void prep_kernel(
    const float* __restrict__ h0, const float* __restrict__ e0,
    const float* __restrict__ e1, unsigned short* __restrict__ An,
    unsigned short* __restrict__ Bn, unsigned short* __restrict__ Cn,
    float* __restrict__ diagPart) {
  __shared__ float sm[4][3];
  const int w = threadIdx.x >> 6, lane = threadIdx.x & 63;
  const int n = blockIdx.x * 4 + w;
  float v0 = h0[(size_t)n * DD + lane];
  float v1 = e0[(size_t)n * DD + lane];
  float v2 = e1[(size_t)n * DD + lane];
  float s00 = wred64(v0 * v0);
  float s11 = wred64(v1 * v1);
  float s22 = wred64(v2 * v2);
  float d01 = wred64(v0 * v1);
  float d02 = wred64(v0 * v2);
  float d12 = wred64(v1 * v2);
  float i0 = rsqrtf(s00), i1 = rsqrtf(s11), i2 = rsqrtf(s22);
  union { __hip_bfloat16 b; unsigned short u; } c0, c1, c2;
  c0.b = __float2bfloat16(v0 * i0 * SQSCALE);
  c1.b = __float2bfloat16(v1 * i1 * SQSCALE);
  c2.b = __float2bfloat16(v2 * i2 * SQSCALE);
  An[(size_t)n * DD + lane] = c0.u;
  Bn[(size_t)n * DD + lane] = c1.u;
  Cn[(size_t)n * DD + lane] = c2.u;
  if (lane == 0) {
    sm[w][0] = d01 * i0 * i1 * TAU_INV;
    sm[w][1] = d02 * i0 * i2 * TAU_INV;
    sm[w][2] = d12 * i1 * i2 * TAU_INV;
  }
  __syncthreads();
  if (threadIdx.x < 3)
    diagPart[threadIdx.x * (NN / 4) + blockIdx.x] =
        sm[0][threadIdx.x] + sm[1][threadIdx.x] + sm[2][threadIdx.x] +
        sm[3][threadIdx.x];
}

// ---------------- sim via bf16 MFMA: per-block row/col exp-sum partials -----
// grid (N/128, N/512, 3), block 256 = 4 waves (2x2 of 64x64 tiles).
// Linearized 16-iter loop, #pragma unroll 1 (VGPR discipline — R4 regression
// was unroll-induced 252 VGPRs), manual 1-deep B prefetch to hide L2 latency.
__global__ __launch_bounds__(256, 4) void sim_mfma_kernel(
    const unsigned short* __restrict__ An, const unsigned short* __restrict__ Bn,
    const unsigned short* __restrict__ Cn, float* __restrict__ rowPart,
    float* __restrict__ colPart) {
  __shared__ float colLds[512];
  __shared__ float rowLds[128];
  const int p = blockIdx.z;
  const unsigned short *a, *b;
  if (p == 0)      { a = An; b = Bn; }
  else if (p == 1) { a = An; b = Cn; }
  else             { a = Bn; b = Cn; }

  const int tid = threadIdx.x;
  const int w = tid >> 6, lane = tid & 63;
  const int wr = w >> 1, wc = w & 1;
  const int lr = lane & 15, lk = lane >> 4;
  const int i0 = blockIdx.x * 128 + wr * 64;

  for (int i = tid; i < 512; i += 256) colLds[i] = 0.f;
  if (tid < 128) rowLds[tid] = 0.f;
  __syncthreads();

  // A fragments: lane holds row (i0+rb*16+lr), k = kh*32 + lk*8 .. +7
  short8 afrag[4][2];
#pragma unroll
  for (int rb = 0; rb < 4; ++rb)
#pragma unroll
    for (int kh = 0; kh < 2; ++kh)
      afrag[rb][kh] = *reinterpret_cast<const short8*>(
          a + (size_t)(i0 + rb * 16 + lr) * DD + kh * 32 + lk * 8);

  float rowacc[4][4];
#pragma unroll
  for (int rb = 0; rb < 4; ++rb)
#pragma unroll
    for (int g = 0; g < 4; ++g) rowacc[rb][g] = 0.f;

  // B row for iteration t: blockIdx.y*512 + wc*64 + (t>>2)*128 + (t&3)*16 + lr
  const unsigned short* bbase =
      b + (size_t)(blockIdx.y * 512 + wc * 64 + lr) * DD + lk * 8;
  const unsigned short* p0 = bbase;  // t=0 offset
  short8 cur0 = *reinterpret_cast<const short8*>(p0);
  short8 cur1 = *reinterpret_cast<const short8*>(p0 + 32);
#pragma unroll 1
  for (int t = 0; t < 16; ++t) {
    const int tn = (t + 1) & 15;
    const unsigned short* np =
        bbase + (size_t)((tn >> 2) * 128 + (tn & 3) * 16) * DD;
    short8 nxt0 = *reinterpret_cast<const short8*>(np);
    short8 nxt1 = *reinterpret_cast<const short8*>(np + 32);

    f32x4 acc[4];
#pragma unroll
    for (int rb = 0; rb < 4; ++rb) {
      acc[rb] = __builtin_amdgcn_mfma_f32_16x16x32_bf16(
          afrag[rb][0], cur0, (f32x4){0.f, 0.f, 0.f, 0.f}, 0, 0, 0);
      acc[rb] = __builtin_amdgcn_mfma_f32_16x16x32_bf16(
          afrag[rb][1], cur1, acc[rb], 0, 0, 0);
    }
    // C/D layout: col = lr, row = lk*4 + g. Inputs prescaled: exp2(acc)=e^{s/tau}
    float colp = 0.f;
#pragma unroll
    for (int rb = 0; rb < 4; ++rb)
#pragma unroll
      for (int g = 0; g < 4; ++g) {
        float ev = __builtin_amdgcn_exp2f(acc[rb][g]);
        rowacc[rb][g] += ev;
        colp += ev;
      }
    colp += __shfl_xor(colp, 16, 64);
    colp += __shfl_xor(colp, 32, 64);
    if (lk == 0)
      atomicAdd(&colLds[(t >> 2) * 128 + wc * 64 + (t & 3) * 16 + lr], colp);
    cur0 = nxt0;
    cur1 = nxt1;
  }

  // row partials: complete over the 16 lr col-lanes, merge wc pair in LDS
#pragma unroll
  for (int rb = 0; rb < 4; ++rb)
#pragma unroll
    for (int g = 0; g < 4; ++g) {
      float v = rowacc[rb][g];
      v += __shfl_xor(v, 1, 64);
      v += __shfl_xor(v, 2, 64);
      v += __shfl_xor(v, 4, 64);
      v += __shfl_xor(v, 8, 64);
      if (lr == 0) atomicAdd(&rowLds[wr * 64 + rb * 16 + lk * 4 + g], v);
    }
  __syncthreads();
  if (tid < 128)
    rowPart[(size_t)(p * 16 + blockIdx.y) * NN + blockIdx.x * 128 + tid] =
        rowLds[tid];
  for (int i = tid; i < 512; i += 256)
    colPart[(size_t)((p * 16 + blockIdx.y) * 64 + blockIdx.x) * 512 + i] =
        colLds[i];
}

// ---------------- semantic attention: sp[t][d] = sum_n tanh(e fc^T + b) -----
__global__ __launch_bounds__(256) void sp_kernel(
    const float* __restrict__ e0, const float* __restrict__ e1,
    const float* __restrict__ fc_w, const float* __restrict__ fc_b,
    float* __restrict__ sp) {
  __shared__ float fcw[64][65];
  __shared__ float es[64][65];
  __shared__ float part[4][64];
  const int t = blockIdx.y;
  const float* __restrict__ e = t ? e1 : e0;
  const int n0 = blockIdx.x * 64;
  const int tid = threadIdx.x;
  for (int i = tid; i < 4096; i += 256) fcw[i >> 6][i & 63] = fc_w[i];
  for (int i = tid; i < 4096; i += 256) {
    int r = i >> 6, c = i & 63;
    es[r][c] = e[(size_t)(n0 + r) * DD + c];
  }
  __syncthreads();
  const int w = tid >> 6, lane = tid & 63;
  const float b = fc_b[lane];
  float partial = 0.f;
  for (int n = w; n < 64; n += 4) {
    float acc = b;
#pragma unroll 8
    for (int k = 0; k < DD; ++k) acc = fmaf(es[n][k], fcw[lane][k], acc);
    acc = fminf(fmaxf(acc, -15.f), 15.f);
    float tt = __expf(2.f * acc);
    partial += (tt - 1.f) * __builtin_amdgcn_rcpf(tt + 1.f);
  }
  part[w][lane] = partial;
  __syncthreads();
  if (tid < 64)
    atomicAdd(&sp[t * DD + tid],
              part[0][tid] + part[1][tid] + part[2][tid] + part[3][tid]);
}

// ---------------- loss partials: reduce rowPart/colPart/diagPart ------------
// grid 216 blocks x 256 (= 6*NN + 6144 units exactly).
__global__ __launch_bounds__(256) void losspart_kernel(
    const float* __restrict__ rowPart, const float* __restrict__ colPart,
    const float* __restrict__ diagPart, float* __restrict__ lossAcc) {
  const int g = blockIdx.x * 256 + threadIdx.x;
  float acc = 0.f;
  if (g < 3 * NN) {
    const int p = g >> 13, r = g & (NN - 1);
    float s = 0.f;
#pragma unroll
    for (int by = 0; by < 16; ++by) s += rowPart[(size_t)(p * 16 + by) * NN + r];
    const float wp = (p == 2) ? ALPHA : 1.f;
    acc = 0.5f * wp * LN2 * __builtin_amdgcn_logf(s);
  } else if (g < 6 * NN) {
    const int gg = g - 3 * NN;
    const int p = gg >> 13, c = gg & (NN - 1);
    const float* base =
        colPart + (size_t)p * (16 * 64 * 512) + (c >> 9) * (64 * 512) + (c & 511);
    float s = 0.f;
#pragma unroll
    for (int bx = 0; bx < 64; ++bx) s += base[bx * 512];
    const float wp = (p == 2) ? ALPHA : 1.f;
    acc = 0.5f * wp * LN2 * __builtin_amdgcn_logf(s);
  } else {
    const int gg = g - 6 * NN;  // < 6144
    const int p = gg >> 11;     // / (NN/4)
    const float wp = (p == 2) ? ALPHA : 1.f;
    acc = -wp * diagPart[gg];
  }
  __shared__ float red[256];
  red[threadIdx.x] = acc;
  __syncthreads();
  for (int s2 = 128; s2 > 0; s2 >>= 1) {
    if (threadIdx.x < s2) red[threadIdx.x] += red[threadIdx.x + s2];
    __syncthreads();
  }
  if (threadIdx.x == 0) atomicAdd(lossAcc, red[0]);
}

// ---------------- z_mc = beta0*e0 + beta1*e1 (+ loss store by block 0) ------
__global__ __launch_bounds__(256) void zmc_kernel(
    const float* __restrict__ e0, const float* __restrict__ e1,
    const float* __restrict__ sp, const float* __restrict__ att_inter,
    const float* __restrict__ lossAcc, float* __restrict__ out) {
  __shared__ float bsh[2];
  const int tid = threadIdx.x;
  if (tid < 64) {
    float a_ = att_inter[tid];
    float s0 = sp[tid] * (1.f / (float)NN) * a_;
    float s1 = sp[DD + tid] * (1.f / (float)NN) * a_;
#pragma unroll
    for (int m = 1; m < 64; m <<= 1) {
      s0 += __shfl_xor(s0, m, 64);
      s1 += __shfl_xor(s1, m, 64);
    }
    if (tid == 0) {
      float mm = fmaxf(s0, s1);
      float b0 = __expf(s0 - mm), b1 = __expf(s1 - mm);
      float inv = 1.f / (b0 + b1);
      bsh[0] = b0 * inv;
      bsh[1] = b1 * inv;
    }
  }
  __syncthreads();
  const float b0 = bsh[0], b1 = bsh[1];
  const int i = blockIdx.x * 256 + tid;
  float4 a = ((const float4*)e0)[i];
  float4 b = ((const float4*)e1)[i];
  float4 o;
  o.x = b0 * a.x + b1 * b.x;
  o.y = b0 * a.y + b1 * b.y;
  o.z = b0 * a.z + b1 * b.z;
  o.w = b0 * a.w + b1 * b.w;
  ((float4*)out)[i] = o;
  if (blockIdx.x == 0 && tid == 0)
    out[(size_t)NN * DD] = lossAcc[0] * (1.f / (float)NN);
}

extern "C" void kernel_launch(void* const* d_in, const int* in_sizes, int n_in,
                              void* d_out, int out_size, void* d_ws,
                              size_t ws_size, hipStream_t stream) {
  const float* h0 = (const float*)d_in[0];
  const float* h1 = (const float*)d_in[1];
  const float* h2 = (const float*)d_in[2];
  const int* nei0 = (const int*)d_in[3];
  const int* nei1 = (const int*)d_in[4];
  const float* att0 = (const float*)d_in[5];
  const float* att1 = (const float*)d_in[6];
  const float* fcw = (const float*)d_in[7];
  const float* fcb = (const float*)d_in[8];
  const float* atti = (const float*)d_in[9];
  float* out = (float*)d_out;

  float* ws = (float*)d_ws;
  float* e0 = ws;                                   // NN*DD
  float* e1 = e0 + (size_t)NN * DD;                 // NN*DD
  float* q = e1 + (size_t)NN * DD;                  // 2*MM = 40000
  unsigned short* An = (unsigned short*)(q + 2 * MM);  // NN*DD bf16 each
  unsigned short* Bn = An + (size_t)NN * DD;
  unsigned short* Cn = Bn + (size_t)NN * DD;
  float* rowPart = (float*)(Cn + (size_t)NN * DD);  // 3*16*NN
  float* colPart = rowPart + (size_t)3 * 16 * NN;   // 3*16*64*512
  float* diagPart = colPart + (size_t)3 * 16 * 64 * 512;  // 3*(NN/4)
  float* sp = diagPart + 3 * (NN / 4);              // 2*DD (zeroed)
  float* lossAcc = sp + 2 * DD;                     // 1    (zeroed)

  hipMemsetAsync(sp, 0, (2 * DD + 1) * sizeof(float), stream);

  q_kernel<<<dim3((2 * MM) / 4), 256, 0, stream>>>(h1, h2, att0, att1, q);
  intra_kernel<<<dim3(NN / 4, 2), 256, 0, stream>>>(h0, h1, h2, nei0, nei1,
                                                    att0, att1, q, e0, e1);
  prep_kernel<<<dim3(NN / 4), 256, 0, stream>>>(h0, e0, e1, An, Bn, Cn,
                                                diagPart);
  sp_kernel<<<dim3(NN / 64, 2), 256, 0, stream>>>(e0, e1, fcw, fcb, sp);
  sim_mfma_kernel<<<dim3(NN / 128, NN / 512, 3), 256, 0, stream>>>(
      An, Bn, Cn, rowPart, colPart);
  losspart_kernel<<<dim3((6 * NN + 6144) / 256), 256, 0, stream>>>(
      rowPart, colPart, diagPart, lossAcc);
  zmc_kernel<<<dim3(NN * DD / 1024), 256, 0, stream>>>(e0, e1, sp, atti,
                                                       lossAcc, out);
}

// Round 6
// 134.457 us; speedup vs baseline: 1.5355x; 1.0032x over previous
//
#include <hip/hip_runtime.h>
#include <hip/hip_bf16.h>
#include <math.h>

#define NN 8192
#define SS 50
#define DD 64
#define MM 20000
#define TAU_INV 2.0f
#define ALPHA 0.5f
#define SQSCALE 1.6986437f  // sqrt(TAU_INV*log2(e)); folded into bf16 inputs
#define LN2 0.69314718056f

typedef __attribute__((ext_vector_type(8))) short short8;  // 8 bf16
typedef __attribute__((ext_vector_type(4))) float f32x4;

__device__ __forceinline__ float wred64(float v) {
#pragma unroll
  for (int m = 1; m < 64; m <<= 1) v += __shfl_xor(v, m, 64);
  return v;
}
__device__ __forceinline__ float wredmax64(float v) {
#pragma unroll
  for (int m = 1; m < 64; m <<= 1) v = fmaxf(v, __shfl_xor(v, m, 64));
  return v;
}

// ---------------- q[t][m] = dot(h_t[m], att_t[D:2D]) ------------------------
__global__ __launch_bounds__(256) void q_kernel(
    const float* __restrict__ h1, const float* __restrict__ h2,
    const float* __restrict__ att0, const float* __restrict__ att1,
    float* __restrict__ q) {
  int gw = blockIdx.x * 4 + (threadIdx.x >> 6);
  int lane = threadIdx.x & 63;
  const float* h = gw < MM ? h1 : h2;
  const float* att = gw < MM ? att0 : att1;
  int row = gw < MM ? gw : gw - MM;
  float v = h[(size_t)row * DD + lane] * att[DD + lane];
  float s = wred64(v);
  if (lane == 0) q[gw] = s;
}

// ---------------- intra attention + ELU -------------------------------------
__global__ __launch_bounds__(256) void intra_kernel(
    const float* __restrict__ h0, const float* __restrict__ h1,
    const float* __restrict__ h2, const int* __restrict__ nei0,
    const int* __restrict__ nei1, const float* __restrict__ att0,
    const float* __restrict__ att1, const float* __restrict__ q,
    float* __restrict__ e0, float* __restrict__ e1) {
  __shared__ float wls[4][SS];
  __shared__ int ils[4][SS];
  const int w = threadIdx.x >> 6, lane = threadIdx.x & 63;
  const int n = blockIdx.x * 4 + w;
  const int type = blockIdx.y;
  const float* __restrict__ h = type ? h2 : h1;
  const int* __restrict__ nei = type ? nei1 : nei0;
  const float* __restrict__ att = type ? att1 : att0;
  const float* __restrict__ qq = q + (size_t)type * MM;
  float* __restrict__ e = type ? e1 : e0;

  float r = h0[(size_t)n * DD + lane];
  float ref = wred64(r * att[lane]);

  float logit = -1e30f;
  int myidx = 0;
  if (lane < SS) {
    myidx = nei[(size_t)n * SS + lane];
    float l = ref + qq[myidx];
    logit = l > 0.f ? l : 0.01f * l;  // leaky_relu slope 0.01
  }
  float mx = wredmax64(logit);
  float ev = lane < SS ? __expf(logit - mx) : 0.f;
  float sum = wred64(ev);
  if (lane < SS) {
    wls[w][lane] = ev / sum;
    ils[w][lane] = myidx;
  }
  __syncthreads();
  float acc = 0.f;
#pragma unroll 10
  for (int s = 0; s < SS; ++s)
    acc = fmaf(wls[w][s], h[(size_t)ils[w][s] * DD + lane], acc);
  e[(size_t)n * DD + lane] = acc > 0.f ? acc : expm1f(acc);  // ELU
}

// ---------------- prep: scaled normalized bf16 copies + diag partials -------
// grid N/4 = 2048 blocks. diagPart layout [p][block] (no atomics).
__global__ __launch_bounds__(256) void prep_kernel(
    const float* __restrict__ h0, const float* __restrict__ e0,
    const float* __restrict__ e1, unsigned short* __restrict__ An,
    unsigned short* __restrict__ Bn, unsigned short* __restrict__ Cn,
    float* __restrict__ diagPart) {
  __shared__ float sm[4][3];
  const int w = threadIdx.x >> 6, lane = threadIdx.x & 63;
  const int n = blockIdx.x * 4 + w;
  float v0 = h0[(size_t)n * DD + lane];
  float v1 = e0[(size_t)n * DD + lane];
  float v2 = e1[(size_t)n * DD + lane];
  float s00 = wred64(v0 * v0);
  float s11 = wred64(v1 * v1);
  float s22 = wred64(v2 * v2);
  float d01 = wred64(v0 * v1);
  float d02 = wred64(v0 * v2);
  float d12 = wred64(v1 * v2);
  float i0 = rsqrtf(s00), i1 = rsqrtf(s11), i2 = rsqrtf(s22);
  union { __hip_bfloat16 b; unsigned short u; } c0, c1, c2;
  c0.b = __float2bfloat16(v0 * i0 * SQSCALE);
  c1.b = __float2bfloat16(v1 * i1 * SQSCALE);
  c2.b = __float2bfloat16(v2 * i2 * SQSCALE);
  An[(size_t)n * DD + lane] = c0.u;
  Bn[(size_t)n * DD + lane] = c1.u;
  Cn[(size_t)n * DD + lane] = c2.u;
  if (lane == 0) {
    sm[w][0] = d01 * i0 * i1 * TAU_INV;
    sm[w][1] = d02 * i0 * i2 * TAU_INV;
    sm[w][2] = d12 * i1 * i2 * TAU_INV;
  }
  __syncthreads();
  if (threadIdx.x < 3)
    diagPart[threadIdx.x * (NN / 4) + blockIdx.x] =
        sm[0][threadIdx.x] + sm[1][threadIdx.x] + sm[2][threadIdx.x] +
        sm[3][threadIdx.x];
}

// ---------------- sim via bf16 MFMA: per-block row/col exp-sum partials -----
// grid (N/128, N/512, 3), block 256 = 4 waves (2x2 of 64x64 tiles).
// Distance-2 B prefetch hides L2 latency; NO in-loop cross-lane/atomic ops:
// col partials go to private LDS slots (one plain ds_write per iteration),
// row partials stay in registers. Epilogue merges slots, plain stores.
__global__ __launch_bounds__(256, 4) void sim_mfma_kernel(
    const unsigned short* __restrict__ An, const unsigned short* __restrict__ Bn,
    const unsigned short* __restrict__ Cn, float* __restrict__ rowPart,
    float* __restrict__ colPart) {
  __shared__ float colLds[8][512];  // [lk*2+wr][col'] — each slot written once
  __shared__ float rowLds[2][128];  // [wc][row']    — plain writes, no atomics
  const int p = blockIdx.z;
  const unsigned short *a, *b;
  if (p == 0)      { a = An; b = Bn; }
  else if (p == 1) { a = An; b = Cn; }
  else             { a = Bn; b = Cn; }

  const int tid = threadIdx.x;
  const int w = tid >> 6, lane = tid & 63;
  const int wr = w >> 1, wc = w & 1;
  const int lr = lane & 15, lk = lane >> 4;
  const int i0 = blockIdx.x * 128 + wr * 64;

  // A fragments: lane holds row (i0+rb*16+lr), k = kh*32 + lk*8 .. +7
  short8 afrag[4][2];
#pragma unroll
  for (int rb = 0; rb < 4; ++rb)
#pragma unroll
    for (int kh = 0; kh < 2; ++kh)
      afrag[rb][kh] = *reinterpret_cast<const short8*>(
          a + (size_t)(i0 + rb * 16 + lr) * DD + kh * 32 + lk * 8);

  float rowacc[4][4];
#pragma unroll
  for (int rb = 0; rb < 4; ++rb)
#pragma unroll
    for (int g = 0; g < 4; ++g) rowacc[rb][g] = 0.f;

  // B row for iteration t: col' = (t>>2)*128 + wc*64 + (t&3)*16 + lr
  const unsigned short* bbase =
      b + (size_t)(blockIdx.y * 512 + wc * 64 + lr) * DD + lk * 8;
#define BADDR(t) (bbase + (size_t)((((t) >> 2) * 128 + ((t) & 3) * 16)) * DD)
  short8 c0 = *reinterpret_cast<const short8*>(BADDR(0));
  short8 c1 = *reinterpret_cast<const short8*>(BADDR(0) + 32);
  short8 m0 = *reinterpret_cast<const short8*>(BADDR(1));
  short8 m1 = *reinterpret_cast<const short8*>(BADDR(1) + 32);
#pragma unroll 1
  for (int t = 0; t < 16; ++t) {
    const int tp = (t + 2) & 15;  // wraps to already-consumed slots: harmless
    const unsigned short* np = BADDR(tp);
    short8 f0 = *reinterpret_cast<const short8*>(np);
    short8 f1 = *reinterpret_cast<const short8*>(np + 32);

    f32x4 acc[4];
#pragma unroll
    for (int rb = 0; rb < 4; ++rb) {
      acc[rb] = __builtin_amdgcn_mfma_f32_16x16x32_bf16(
          afrag[rb][0], c0, (f32x4){0.f, 0.f, 0.f, 0.f}, 0, 0, 0);
      acc[rb] = __builtin_amdgcn_mfma_f32_16x16x32_bf16(
          afrag[rb][1], c1, acc[rb], 0, 0, 0);
    }
    // C/D layout: col = lr, row = lk*4 + g. Inputs prescaled: exp2(acc)=e^{s/tau}
    float colp = 0.f;
#pragma unroll
    for (int rb = 0; rb < 4; ++rb)
#pragma unroll
      for (int g = 0; g < 4; ++g) {
        float ev = __builtin_amdgcn_exp2f(acc[rb][g]);
        rowacc[rb][g] += ev;
        colp += ev;
      }
    colLds[lk * 2 + wr][(t >> 2) * 128 + wc * 64 + (t & 3) * 16 + lr] = colp;
    c0 = m0; c1 = m1; m0 = f0; m1 = f1;
  }
#undef BADDR

  // row partials: reduce over the 16 lr col-lanes, plain write per wc slot
#pragma unroll
  for (int rb = 0; rb < 4; ++rb)
#pragma unroll
    for (int g = 0; g < 4; ++g) {
      float v = rowacc[rb][g];
      v += __shfl_xor(v, 1, 64);
      v += __shfl_xor(v, 2, 64);
      v += __shfl_xor(v, 4, 64);
      v += __shfl_xor(v, 8, 64);
      if (lr == 0) rowLds[wc][wr * 64 + rb * 16 + lk * 4 + g] = v;
    }
  __syncthreads();
  if (tid < 128)
    rowPart[(size_t)(p * 16 + blockIdx.y) * NN + blockIdx.x * 128 + tid] =
        rowLds[0][tid] + rowLds[1][tid];
  for (int i = tid; i < 512; i += 256) {
    float s = 0.f;
#pragma unroll
    for (int sl = 0; sl < 8; ++sl) s += colLds[sl][i];
    colPart[(size_t)((p * 16 + blockIdx.y) * 64 + blockIdx.x) * 512 + i] = s;
  }
}

// ---------------- semantic attention: sp[t][d] = sum_n tanh(e fc^T + b) -----
__global__ __launch_bounds__(256) void sp_kernel(
    const float* __restrict__ e0, const float* __restrict__ e1,
    const float* __restrict__ fc_w, const float* __restrict__ fc_b,
    float* __restrict__ sp) {
  __shared__ float fcw[64][65];
  __shared__ float es[64][65];
  __shared__ float part[4][64];
  const int t = blockIdx.y;
  const float* __restrict__ e = t ? e1 : e0;
  const int n0 = blockIdx.x * 64;
  const int tid = threadIdx.x;
  for (int i = tid; i < 4096; i += 256) fcw[i >> 6][i & 63] = fc_w[i];
  for (int i = tid; i < 4096; i += 256) {
    int r = i >> 6, c = i & 63;
    es[r][c] = e[(size_t)(n0 + r) * DD + c];
  }
  __syncthreads();
  const int w = tid >> 6, lane = tid & 63;
  const float b = fc_b[lane];
  float partial = 0.f;
  for (int n = w; n < 64; n += 4) {
    float acc = b;
#pragma unroll 8
    for (int k = 0; k < DD; ++k) acc = fmaf(es[n][k], fcw[lane][k], acc);
    acc = fminf(fmaxf(acc, -15.f), 15.f);
    float tt = __expf(2.f * acc);
    partial += (tt - 1.f) * __builtin_amdgcn_rcpf(tt + 1.f);
  }
  part[w][lane] = partial;
  __syncthreads();
  if (tid < 64)
    atomicAdd(&sp[t * DD + tid],
              part[0][tid] + part[1][tid] + part[2][tid] + part[3][tid]);
}

// ---------------- loss partials: reduce rowPart/colPart/diagPart ------------
// grid 216 blocks x 256 (= 6*NN + 6144 units exactly).
__global__ __launch_bounds__(256) void losspart_kernel(
    const float* __restrict__ rowPart, const float* __restrict__ colPart,
    const float* __restrict__ diagPart, float* __restrict__ lossAcc) {
  const int g = blockIdx.x * 256 + threadIdx.x;
  float acc = 0.f;
  if (g < 3 * NN) {
    const int p = g >> 13, r = g & (NN - 1);
    float s = 0.f;
#pragma unroll
    for (int by = 0; by < 16; ++by) s += rowPart[(size_t)(p * 16 + by) * NN + r];
    const float wp = (p == 2) ? ALPHA : 1.f;
    acc = 0.5f * wp * LN2 * __builtin_amdgcn_logf(s);
  } else if (g < 6 * NN) {
    const int gg = g - 3 * NN;
    const int p = gg >> 13, c = gg & (NN - 1);
    const float* base =
        colPart + (size_t)p * (16 * 64 * 512) + (c >> 9) * (64 * 512) + (c & 511);
    float s = 0.f;
#pragma unroll
    for (int bx = 0; bx < 64; ++bx) s += base[bx * 512];
    const float wp = (p == 2) ? ALPHA : 1.f;
    acc = 0.5f * wp * LN2 * __builtin_amdgcn_logf(s);
  } else {
    const int gg = g - 6 * NN;  // < 6144
    const int p = gg >> 11;     // / (NN/4)
    const float wp = (p == 2) ? ALPHA : 1.f;
    acc = -wp * diagPart[gg];
  }
  __shared__ float red[256];
  red[threadIdx.x] = acc;
  __syncthreads();
  for (int s2 = 128; s2 > 0; s2 >>= 1) {
    if (threadIdx.x < s2) red[threadIdx.x] += red[threadIdx.x + s2];
    __syncthreads();
  }
  if (threadIdx.x == 0) atomicAdd(lossAcc, red[0]);
}

// ---------------- z_mc = beta0*e0 + beta1*e1 (+ loss store by block 0) ------
__global__ __launch_bounds__(256) void zmc_kernel(
    const float* __restrict__ e0, const float* __restrict__ e1,
    const float* __restrict__ sp, const float* __restrict__ att_inter,
    const float* __restrict__ lossAcc, float* __restrict__ out) {
  __shared__ float bsh[2];
  const int tid = threadIdx.x;
  if (tid < 64) {
    float a_ = att_inter[tid];
    float s0 = sp[tid] * (1.f / (float)NN) * a_;
    float s1 = sp[DD + tid] * (1.f / (float)NN) * a_;
#pragma unroll
    for (int m = 1; m < 64; m <<= 1) {
      s0 += __shfl_xor(s0, m, 64);
      s1 += __shfl_xor(s1, m, 64);
    }
    if (tid == 0) {
      float mm = fmaxf(s0, s1);
      float b0 = __expf(s0 - mm), b1 = __expf(s1 - mm);
      float inv = 1.f / (b0 + b1);
      bsh[0] = b0 * inv;
      bsh[1] = b1 * inv;
    }
  }
  __syncthreads();
  const float b0 = bsh[0], b1 = bsh[1];
  const int i = blockIdx.x * 256 + tid;
  float4 a = ((const float4*)e0)[i];
  float4 b = ((const float4*)e1)[i];
  float4 o;
  o.x = b0 * a.x + b1 * b.x;
  o.y = b0 * a.y + b1 * b.y;
  o.z = b0 * a.z + b1 * b.z;
  o.w = b0 * a.w + b1 * b.w;
  ((float4*)out)[i] = o;
  if (blockIdx.x == 0 && tid == 0)
    out[(size_t)NN * DD] = lossAcc[0] * (1.f / (float)NN);
}

extern "C" void kernel_launch(void* const* d_in, const int* in_sizes, int n_in,
                              void* d_out, int out_size, void* d_ws,
                              size_t ws_size, hipStream_t stream) {
  const float* h0 = (const float*)d_in[0];
  const float* h1 = (const float*)d_in[1];
  const float* h2 = (const float*)d_in[2];
  const int* nei0 = (const int*)d_in[3];
  const int* nei1 = (const int*)d_in[4];
  const float* att0 = (const float*)d_in[5];
  const float* att1 = (const float*)d_in[6];
  const float* fcw = (const float*)d_in[7];
  const float* fcb = (const float*)d_in[8];
  const float* atti = (const float*)d_in[9];
  float* out = (float*)d_out;

  float* ws = (float*)d_ws;
  float* e0 = ws;                                   // NN*DD
  float* e1 = e0 + (size_t)NN * DD;                 // NN*DD
  float* q = e1 + (size_t)NN * DD;                  // 2*MM = 40000
  unsigned short* An = (unsigned short*)(q + 2 * MM);  // NN*DD bf16 each
  unsigned short* Bn = An + (size_t)NN * DD;
  unsigned short* Cn = Bn + (size_t)NN * DD;
  float* rowPart = (float*)(Cn + (size_t)NN * DD);  // 3*16*NN
  float* colPart = rowPart + (size_t)3 * 16 * NN;   // 3*16*64*512
  float* diagPart = colPart + (size_t)3 * 16 * 64 * 512;  // 3*(NN/4)
  float* sp = diagPart + 3 * (NN / 4);              // 2*DD (zeroed)
  float* lossAcc = sp + 2 * DD;                     // 1    (zeroed)

  hipMemsetAsync(sp, 0, (2 * DD + 1) * sizeof(float), stream);

  q_kernel<<<dim3((2 * MM) / 4), 256, 0, stream>>>(h1, h2, att0, att1, q);
  intra_kernel<<<dim3(NN / 4, 2), 256, 0, stream>>>(h0, h1, h2, nei0, nei1,
                                                    att0, att1, q, e0, e1);
  prep_kernel<<<dim3(NN / 4), 256, 0, stream>>>(h0, e0, e1, An, Bn, Cn,
                                                diagPart);
  sp_kernel<<<dim3(NN / 64, 2), 256, 0, stream>>>(e0, e1, fcw, fcb, sp);
  sim_mfma_kernel<<<dim3(NN / 128, NN / 512, 3), 256, 0, stream>>>(
      An, Bn, Cn, rowPart, colPart);
  losspart_kernel<<<dim3((6 * NN + 6144) / 256), 256, 0, stream>>>(
      rowPart, colPart, diagPart, lossAcc);
  zmc_kernel<<<dim3(NN * DD / 1024), 256, 0, stream>>>(e0, e1, sp, atti,
                                                       lossAcc, out);
}